// Round 10
// baseline (1716.503 us; speedup 1.0000x reference)
//
#include <hip/hip_runtime.h>
#include <stdint.h>

#define NSEQ 512
#define XS 104   // xin row stride (shorts): 96 cond + pad
#define AS 136   // act row stride (shorts)
#define PS 36    // part row stride (f32): 16 float2 slots + pad
#define EPS 1e-5f

typedef short bfrag __attribute__((ext_vector_type(8)));
typedef float f4 __attribute__((ext_vector_type(4)));
#define MFMA16 __builtin_amdgcn_mfma_f32_16x16x32_bf16

__device__ __forceinline__ unsigned short f2bf(float f){
  uint32_t u = __float_as_uint(f);
  u += 0x7FFFu + ((u>>16)&1u);   // RNE
  return (unsigned short)(u>>16);
}
__device__ __forceinline__ uint32_t pk2bf(float a, float b){
  uint32_t r;
  asm("v_cvt_pk_bf16_f32 %0, %1, %2" : "=v"(r) : "v"(a), "v"(b));
  return r;
}
__device__ __forceinline__ float tanh_fast(float v){
  float e = __builtin_amdgcn_exp2f(v * 2.8853900817779268f);  // e^(2v)
  float r = __builtin_amdgcn_rcpf(e + 1.f);
  return fmaf(-2.f, r, 1.f);
}
// LDS-only barrier: global loads/stores stay in flight across it
__device__ __forceinline__ void lds_barrier(){
  asm volatile("s_waitcnt lgkmcnt(0)" ::: "memory");
  __builtin_amdgcn_s_barrier();
  asm volatile("" ::: "memory");
}

__device__ __forceinline__ void stats_write(const float (&h0)[4], const float (&h1)[4],
                                            float* __restrict__ part,
                                            const int w, const int lg, const int lc){
  const float s = ((h0[0]+h0[1])+(h0[2]+h0[3])) + ((h1[0]+h1[1])+(h1[2]+h1[3]));
  const float q = (fmaf(h0[0],h0[0], h0[1]*h0[1]) + fmaf(h0[2],h0[2], h0[3]*h0[3]))
                + (fmaf(h1[0],h1[0], h1[1]*h1[1]) + fmaf(h1[2],h1[2], h1[3]*h1[3]));
  *(float2*)(part + lc*PS + (w*4+lg)*2) = make_float2(s, q);
}

__device__ __forceinline__ void ln_tanh_store(const float (&h0)[4], const float (&h1)[4],
    const float (&gd)[2][4], const float (&bed)[2][4],
    const float* __restrict__ part, unsigned short* __restrict__ actb,
    const int w, const int lg, const int lc){
  const float* pr = part + lc*PS;
  const f4 p0=*(const f4*)(pr),    p1=*(const f4*)(pr+4),  p2=*(const f4*)(pr+8),  p3=*(const f4*)(pr+12);
  const f4 p4=*(const f4*)(pr+16), p5=*(const f4*)(pr+20), p6=*(const f4*)(pr+24), p7=*(const f4*)(pr+28);
  const float ss = (((p0.x+p0.z)+(p1.x+p1.z)) + ((p2.x+p2.z)+(p3.x+p3.z)))
                 + (((p4.x+p4.z)+(p5.x+p5.z)) + ((p6.x+p6.z)+(p7.x+p7.z)));
  const float qq = (((p0.y+p0.w)+(p1.y+p1.w)) + ((p2.y+p2.w)+(p3.y+p3.w)))
                 + (((p4.y+p4.w)+(p5.y+p5.w)) + ((p6.y+p6.w)+(p7.y+p7.w)));
  const float mu = ss * 0.0078125f;
  const float rs = rsqrtf(fmaf(qq, 0.0078125f, -mu*mu) + EPS);
  float e0[4], e1[4];
#pragma unroll
  for (int g=0; g<4; ++g){
    e0[g] = tanh_fast(fmaf((h0[g]-mu)*rs, gd[0][g], bed[0][g]));
    e1[g] = tanh_fast(fmaf((h1[g]-mu)*rs, gd[1][g], bed[1][g]));
  }
  uint4 pk4;
  pk4.x = pk2bf(e0[0],e0[1]); pk4.y = pk2bf(e0[2],e0[3]);
  pk4.z = pk2bf(e1[0],e1[1]); pk4.w = pk2bf(e1[2],e1[3]);
  *(uint4*)(actb + lc*AS + w*32 + lg*8) = pk4;
}

__global__ __launch_bounds__(256, 1)
void latent_ode_v10(const float* __restrict__ z0, const float* __restrict__ tt,
                    const float* __restrict__ cond,
                    const float* __restrict__ W0, const float* __restrict__ b0,
                    const float* __restrict__ g0, const float* __restrict__ be0,
                    const float* __restrict__ W1, const float* __restrict__ b1,
                    const float* __restrict__ g1, const float* __restrict__ be1,
                    const float* __restrict__ W2, const float* __restrict__ b2,
                    const float* __restrict__ g2, const float* __restrict__ be2,
                    const float* __restrict__ Wo, const float* __restrict__ bo,
                    float* __restrict__ out)
{
  __shared__ __align__(16) unsigned short xin[16*XS];   // cond only
  __shared__ __align__(16) unsigned short act[16*AS];
  __shared__ __align__(16) float part[16*PS];

  const int t  = threadIdx.x;     // 0..255, 4 waves
  const int w  = t >> 6;
  const int l  = t & 63;
  const int lg = l >> 4;
  const int lc = l & 15;
  const int r0 = blockIdx.x * 16;

  // ---- hidden-layer weight fragments (v9 mapping: lane owns 8 contiguous neurons)
  bfrag A0z[2][2], A0c[2][3], A1f[2][4], A2f[2][4];
#pragma unroll
  for (int nt=0; nt<2; ++nt){
    const int col = w*32 + nt*4 + ((lc>>2)<<3) + (lc&3);
#pragma unroll
    for (int kt=0; kt<2; ++kt){
      union { bfrag v; unsigned short u[8]; } r;
#pragma unroll
      for (int j=0; j<8; ++j) r.u[j] = f2bf(W0[(size_t)(kt*32 + lg*8 + j)*128 + col]);
      A0z[nt][kt] = r.v;
    }
#pragma unroll
    for (int s=0; s<3; ++s){
      union { bfrag v; unsigned short u[8]; } r;
#pragma unroll
      for (int j=0; j<8; ++j) r.u[j] = f2bf(W0[(size_t)(64 + s*32 + lg*8 + j)*128 + col]);
      A0c[nt][s] = r.v;
    }
#pragma unroll
    for (int kt=0; kt<4; ++kt){
      union { bfrag v; unsigned short u[8]; } r1, r2;
#pragma unroll
      for (int j=0; j<8; ++j){
        const int k = kt*32 + lg*8 + j;
        r1.u[j] = f2bf(W1[(size_t)k*128 + col]);
        r2.u[j] = f2bf(W2[(size_t)k*128 + col]);
      }
      A1f[nt][kt] = r1.v; A2f[nt][kt] = r2.v;
    }
  }
  // ---- Lo: redundant all-latent, lambda-permuted columns so each lane ends
  // holding exactly its next-step L0 B-frag latents {lg*8+j, 32+lg*8+j}.
  bfrag Aof[4][4];
#pragma unroll
  for (int nt=0; nt<4; ++nt){
    const int colM = (nt&1)*32 + ((lc>>2)<<3) + ((nt>>1)<<2) + (lc&3);
#pragma unroll
    for (int kt=0; kt<4; ++kt){
      union { bfrag v; unsigned short u[8]; } r;
#pragma unroll
      for (int j=0; j<8; ++j)
        r.u[j] = f2bf(Wo[(size_t)(kt*32 + lg*8 + j)*64 + colM]);
      Aof[nt][kt] = r.v;
    }
  }
  float bd0[2][4], gd0[2][4], bed0[2][4];
  float bd1[2][4], gd1[2][4], bed1[2][4];
  float bd2[2][4], gd2[2][4], bed2[2][4];
  float bo_d[4][4];
#pragma unroll
  for (int nt=0; nt<2; ++nt){
#pragma unroll
    for (int g=0; g<4; ++g){
      const int n = w*32 + lg*8 + nt*4 + g;
      bd0[nt][g]=b0[n]; gd0[nt][g]=g0[n]; bed0[nt][g]=be0[n];
      bd1[nt][g]=b1[n]; gd1[nt][g]=g1[n]; bed1[nt][g]=be1[n];
      bd2[nt][g]=b2[n]; gd2[nt][g]=g2[n]; bed2[nt][g]=be2[n];
    }
  }
#pragma unroll
  for (int nt=0; nt<4; ++nt)
#pragma unroll
    for (int g=0; g<4; ++g)
      bo_d[nt][g] = bo[(nt&1)*32 + lg*8 + ((nt>>1)<<2) + g];

  // ---- t pipeline
  const float* tp = tt + (size_t)(r0+lc)*NSEQ;
  float tcv = tp[0], tnv = tp[1];

  // ---- z in registers (lambda layout) + out step 0 + packed B-frags
  f4 zr[4];
  union { bfrag v; uint32_t u[4]; } zu0, zu1;
  {
    float* ob0 = out + ((size_t)(r0+lc)*NSEQ)*64;
#pragma unroll
    for (int nt=0; nt<4; ++nt){
      const int lb = (nt&1)*32 + lg*8 + ((nt>>1)<<2);
      zr[nt] = *(const f4*)(z0 + (size_t)(r0+lc)*64 + lb);
      *(f4*)(ob0 + lb) = zr[nt];
    }
    zu0.u[0]=pk2bf(zr[0][0],zr[0][1]); zu0.u[1]=pk2bf(zr[0][2],zr[0][3]);
    zu0.u[2]=pk2bf(zr[2][0],zr[2][1]); zu0.u[3]=pk2bf(zr[2][2],zr[2][3]);
    zu1.u[0]=pk2bf(zr[1][0],zr[1][1]); zu1.u[1]=pk2bf(zr[1][2],zr[1][3]);
    zu1.u[2]=pk2bf(zr[3][0],zr[3][1]); zu1.u[3]=pk2bf(zr[3][2],zr[3][3]);
  }

  // ---- cond staging: 12 threads/row x 8 f32 -> one b128 bf16 write
  const bool stgW = (t < 192);
  const int srow = t / 12, s8 = t - srow*12;
  const float* cptr = cond + ((size_t)(r0+srow)*NSEQ)*96 + s8*8;
  float4 pf0 = {0,0,0,0}, pf1 = {0,0,0,0};
  if (stgW){
    const float4 c0 = *(const float4*)(cptr);
    const float4 c1 = *(const float4*)(cptr + 4);
    uint4 u;
    u.x = pk2bf(c0.x,c0.y); u.y = pk2bf(c0.z,c0.w);
    u.z = pk2bf(c1.x,c1.y); u.w = pk2bf(c1.z,c1.w);
    *(uint4*)(xin + srow*XS + s8*8) = u;
    pf0 = *(const float4*)(cptr + 96);
    pf1 = *(const float4*)(cptr + 100);
  }
  lds_barrier();

  // ---- prologue: preacc cond(0) + L0(0) + stats0
  f4 apC[2];
  float h0[4], h1[4];
  {
    const int o = lc*XS + lg*8;
    const bfrag c0 = *(const bfrag*)(xin + o);
    const bfrag c1 = *(const bfrag*)(xin + o + 32);
    const bfrag c2 = *(const bfrag*)(xin + o + 64);
    const f4 z4 = {0,0,0,0};
#pragma unroll
    for (int nt=0; nt<2; ++nt){
      f4 a = MFMA16(A0c[nt][0], c0, z4, 0,0,0);
      a = MFMA16(A0c[nt][1], c1, a, 0,0,0);
      a = MFMA16(A0c[nt][2], c2, a, 0,0,0);
      apC[nt] = a;
    }
    f4 d0 = MFMA16(A0z[0][0], zu0.v, z4, 0,0,0);
    f4 d1 = MFMA16(A0z[1][0], zu0.v, z4, 0,0,0);
    d0 = MFMA16(A0z[0][1], zu1.v, d0, 0,0,0);
    d1 = MFMA16(A0z[1][1], zu1.v, d1, 0,0,0);
#pragma unroll
    for (int g=0; g<4; ++g){
      h0[g] = (d0[g] + apC[0][g]) + bd0[0][g];
      h1[g] = (d1[g] + apC[1][g]) + bd0[1][g];
    }
    stats_write(h0, h1, part, w, lg, lc);
  }
  lds_barrier();
  // ---- stage cond(1); pf = cond(2)
  if (stgW){
    uint4 u;
    u.x = pk2bf(pf0.x,pf0.y); u.y = pk2bf(pf0.z,pf0.w);
    u.z = pk2bf(pf1.x,pf1.y); u.w = pk2bf(pf1.z,pf1.w);
    *(uint4*)(xin + srow*XS + s8*8) = u;
    pf0 = *(const float4*)(cptr + 2*96);
    pf1 = *(const float4*)(cptr + 2*96 + 4);
  }
  lds_barrier();

  for (int i=0; i<NSEQ-1; ++i){
    // ---- S2: LN0 + preacc cond(i+1)
    {
      const int o = lc*XS + lg*8;
      const bfrag c0 = *(const bfrag*)(xin + o);
      const bfrag c1 = *(const bfrag*)(xin + o + 32);
      const bfrag c2 = *(const bfrag*)(xin + o + 64);
      const f4 z4 = {0,0,0,0};
      f4 a0 = MFMA16(A0c[0][0], c0, z4, 0,0,0);
      f4 a1 = MFMA16(A0c[1][0], c0, z4, 0,0,0);
      a0 = MFMA16(A0c[0][1], c1, a0, 0,0,0);
      a1 = MFMA16(A0c[1][1], c1, a1, 0,0,0);
      a0 = MFMA16(A0c[0][2], c2, a0, 0,0,0);
      a1 = MFMA16(A0c[1][2], c2, a1, 0,0,0);
      ln_tanh_store(h0, h1, gd0, bed0, part, act, w, lg, lc);
      apC[0] = a0; apC[1] = a1;
    }
    lds_barrier();

    // ---- S3: L1 + stats
    {
      const int o = lc*AS + lg*8;
      const bfrag b0f = *(const bfrag*)(act + o);
      const bfrag b1f = *(const bfrag*)(act + o + 32);
      const bfrag b2f = *(const bfrag*)(act + o + 64);
      const bfrag b3f = *(const bfrag*)(act + o + 96);
      const f4 z4 = {0,0,0,0};
      f4 ca0 = MFMA16(A1f[0][0], b0f, z4, 0,0,0);
      f4 cb0 = MFMA16(A1f[0][1], b1f, z4, 0,0,0);
      f4 ca1 = MFMA16(A1f[1][0], b0f, z4, 0,0,0);
      f4 cb1 = MFMA16(A1f[1][1], b1f, z4, 0,0,0);
      ca0 = MFMA16(A1f[0][2], b2f, ca0, 0,0,0);
      cb0 = MFMA16(A1f[0][3], b3f, cb0, 0,0,0);
      ca1 = MFMA16(A1f[1][2], b2f, ca1, 0,0,0);
      cb1 = MFMA16(A1f[1][3], b3f, cb1, 0,0,0);
#pragma unroll
      for (int g=0; g<4; ++g){
        h0[g] = (ca0[g]+cb0[g]) + bd1[0][g];
        h1[g] = (ca1[g]+cb1[g]) + bd1[1][g];
      }
      stats_write(h0, h1, part, w, lg, lc);
    }
    lds_barrier();

    // ---- S4: LN1
    ln_tanh_store(h0, h1, gd1, bed1, part, act, w, lg, lc);
    lds_barrier();

    // ---- S5: L2 + stats
    {
      const int o = lc*AS + lg*8;
      const bfrag b0f = *(const bfrag*)(act + o);
      const bfrag b1f = *(const bfrag*)(act + o + 32);
      const bfrag b2f = *(const bfrag*)(act + o + 64);
      const bfrag b3f = *(const bfrag*)(act + o + 96);
      const f4 z4 = {0,0,0,0};
      f4 ca0 = MFMA16(A2f[0][0], b0f, z4, 0,0,0);
      f4 cb0 = MFMA16(A2f[0][1], b1f, z4, 0,0,0);
      f4 ca1 = MFMA16(A2f[1][0], b0f, z4, 0,0,0);
      f4 cb1 = MFMA16(A2f[1][1], b1f, z4, 0,0,0);
      ca0 = MFMA16(A2f[0][2], b2f, ca0, 0,0,0);
      cb0 = MFMA16(A2f[0][3], b3f, cb0, 0,0,0);
      ca1 = MFMA16(A2f[1][2], b2f, ca1, 0,0,0);
      cb1 = MFMA16(A2f[1][3], b3f, cb1, 0,0,0);
#pragma unroll
      for (int g=0; g<4; ++g){
        h0[g] = (ca0[g]+cb0[g]) + bd2[0][g];
        h1[g] = (ca1[g]+cb1[g]) + bd2[1][g];
      }
      stats_write(h0, h1, part, w, lg, lc);
    }
    lds_barrier();

    // ---- S6: LN2
    ln_tanh_store(h0, h1, gd2, bed2, part, act, w, lg, lc);
    lds_barrier();

    // ---- S1: redundant Lo + Euler + out + in-reg pack + L0(i+1) + stats + staging
    {
      const int ip2 = (i+2 <= NSEQ-1) ? (i+2) : (NSEQ-1);
      const float tfv = tp[ip2];
      const int o = lc*AS + lg*8;
      const bfrag b0f = *(const bfrag*)(act + o);
      const bfrag b1f = *(const bfrag*)(act + o + 32);
      const bfrag b2f = *(const bfrag*)(act + o + 64);
      const bfrag b3f = *(const bfrag*)(act + o + 96);
      const f4 z4 = {0,0,0,0};
      const float dt = tnv - tcv;
      f4 zn[4];
#pragma unroll
      for (int nt=0; nt<4; ++nt){
        f4 aa = MFMA16(Aof[nt][0], b0f, z4, 0,0,0);
        f4 ab = MFMA16(Aof[nt][1], b1f, z4, 0,0,0);
        aa = MFMA16(Aof[nt][2], b2f, aa, 0,0,0);
        ab = MFMA16(Aof[nt][3], b3f, ab, 0,0,0);
#pragma unroll
        for (int g=0; g<4; ++g)
          zn[nt][g] = fmaf(dt, (aa[g]+ab[g]) + bo_d[nt][g], zr[nt][g]);
        zr[nt] = zn[nt];
      }
      float* ob = out + ((size_t)(r0+lc)*NSEQ + (size_t)(i+1))*64;
#pragma unroll
      for (int nt=0; nt<4; ++nt)
        *(f4*)(ob + (nt&1)*32 + lg*8 + ((nt>>1)<<2)) = zn[nt];
      zu0.u[0]=pk2bf(zn[0][0],zn[0][1]); zu0.u[1]=pk2bf(zn[0][2],zn[0][3]);
      zu0.u[2]=pk2bf(zn[2][0],zn[2][1]); zu0.u[3]=pk2bf(zn[2][2],zn[2][3]);
      zu1.u[0]=pk2bf(zn[1][0],zn[1][1]); zu1.u[1]=pk2bf(zn[1][2],zn[1][3]);
      zu1.u[2]=pk2bf(zn[3][0],zn[3][1]); zu1.u[3]=pk2bf(zn[3][2],zn[3][3]);
      if (i < NSEQ-2){
        // L0 of step i+1 (z in regs, cond via apC from S2)
        f4 d0 = MFMA16(A0z[0][0], zu0.v, z4, 0,0,0);
        f4 d1 = MFMA16(A0z[1][0], zu0.v, z4, 0,0,0);
        d0 = MFMA16(A0z[0][1], zu1.v, d0, 0,0,0);
        d1 = MFMA16(A0z[1][1], zu1.v, d1, 0,0,0);
#pragma unroll
        for (int g=0; g<4; ++g){
          h0[g] = (d0[g] + apC[0][g]) + bd0[0][g];
          h1[g] = (d1[g] + apC[1][g]) + bd0[1][g];
        }
        stats_write(h0, h1, part, w, lg, lc);
        if (stgW){
          uint4 u;
          u.x = pk2bf(pf0.x,pf0.y); u.y = pk2bf(pf0.z,pf0.w);
          u.z = pk2bf(pf1.x,pf1.y); u.w = pk2bf(pf1.z,pf1.w);
          *(uint4*)(xin + srow*XS + s8*8) = u;
          if (i < NSEQ-3){
            pf0 = *(const float4*)(cptr + (size_t)(i+3)*96);
            pf1 = *(const float4*)(cptr + (size_t)(i+3)*96 + 4);
          }
        }
      }
      tcv = tnv; tnv = tfv;
    }
    lds_barrier();
  }
}

extern "C" void kernel_launch(void* const* d_in, const int* in_sizes, int n_in,
                              void* d_out, int out_size, void* d_ws, size_t ws_size,
                              hipStream_t stream) {
  const float* z0   = (const float*)d_in[0];
  const float* tt   = (const float*)d_in[1];
  const float* cond = (const float*)d_in[2];
  const float* W0   = (const float*)d_in[3];
  const float* b0   = (const float*)d_in[4];
  const float* g0   = (const float*)d_in[5];
  const float* be0  = (const float*)d_in[6];
  const float* W1   = (const float*)d_in[7];
  const float* b1   = (const float*)d_in[8];
  const float* g1   = (const float*)d_in[9];
  const float* be1  = (const float*)d_in[10];
  const float* W2   = (const float*)d_in[11];
  const float* b2   = (const float*)d_in[12];
  const float* g2   = (const float*)d_in[13];
  const float* be2  = (const float*)d_in[14];
  const float* Wo   = (const float*)d_in[15];
  const float* bo   = (const float*)d_in[16];
  float* out = (float*)d_out;

  hipLaunchKernelGGL(latent_ode_v10, dim3(64), dim3(256), 0, stream,
                     z0, tt, cond, W0, b0, g0, be0, W1, b1, g1, be1,
                     W2, b2, g2, be2, Wo, bo, out);
}